// Round 3
// baseline (334.469 us; speedup 1.0000x reference)
//
#include <hip/hip_runtime.h>
#include <math.h>

// GaussianAvatar: LBS skinning + tangent frames + gaussian param finalize.
// R3: split face-normal compute from vertex gather (1-hop CSR gather of
// precomputed float4 face normals), float4-padded Vw/nrm, vectorized loads.
// Falls back to the R2 structure if ws_size < fast-path requirement.
namespace {
constexpr int kB = 32;
constexpr int kV = 25000;
constexpr int kJ = 20;
constexpr int kF = 50000;
constexpr int kN = 200000;

constexpr float kEps = 1e-8f;

// output layout (flat float32, concatenated in return order)
constexpr size_t OFF_MEANS  = 0;
constexpr size_t OFF_COLORS = (size_t)kB * kN * 3;
constexpr size_t OFF_OPAC   = OFF_COLORS + (size_t)kB * kN * 3;
constexpr size_t OFF_SCALE  = OFF_OPAC + (size_t)kB * kN;
constexpr size_t OFF_ROT    = OFF_SCALE + (size_t)kB * kN * 3;

// ---- fast-path workspace layout (bytes), all 16B aligned ----
constexpr size_t FWS_A       = 0;                        // B*J*12 f
constexpr size_t FWS_VW      = 32768;                    // B*V*4 f = 12.8 MB
constexpr size_t FWS_FN      = FWS_VW + 12800000;        // B*F*4 f = 25.6 MB
constexpr size_t FWS_NRM     = FWS_FN + 25600000;        // B*V*4 f = 12.8 MB
constexpr size_t FWS_CNT     = FWS_NRM + 12800000;
constexpr size_t FWS_OFFS    = FWS_CNT + 100032;
constexpr size_t FWS_ENTRIES = FWS_OFFS + 100032;
constexpr size_t FWS_END     = FWS_ENTRIES + 600000;     // ~52.04 MB

// ---- fallback (R2) workspace layout ----
constexpr size_t SWS_A       = 0;
constexpr size_t SWS_VW      = 32768;                    // B*V*3 f
constexpr size_t SWS_NRM     = SWS_VW + 9600000;
constexpr size_t SWS_CNT     = SWS_NRM + 9600000;
constexpr size_t SWS_OFFS    = SWS_CNT + 100032;
constexpr size_t SWS_ENTRIES = SWS_OFFS + 100032;
}

// ---------------------------------------------------------------------------
// CSR build: count, scan (one block), fill.
// ---------------------------------------------------------------------------
__global__ void count_kernel(const int* __restrict__ faces,
                             int* __restrict__ cnt) {
    int f = blockIdx.x * blockDim.x + threadIdx.x;
    if (f >= kF) return;
    atomicAdd(&cnt[faces[f * 3 + 0]], 1);
    atomicAdd(&cnt[faces[f * 3 + 1]], 1);
    atomicAdd(&cnt[faces[f * 3 + 2]], 1);
}

__global__ void scan_kernel(const int* __restrict__ cnt,
                            int* __restrict__ off) {
    __shared__ int partial[1024];
    int t = threadIdx.x;
    int lo = t * 25;
    int hi = min(lo + 25, kV);
    int s = 0;
    for (int i = lo; i < hi; ++i) s += cnt[i];
    partial[t] = s;
    __syncthreads();
    if (t == 0) {
        int acc = 0;
        for (int i = 0; i < 1024; ++i) {
            int v = partial[i];
            partial[i] = acc;
            acc += v;
        }
    }
    __syncthreads();
    int acc = partial[t];
    for (int i = lo; i < hi; ++i) {
        off[i] = acc;
        acc += cnt[i];
    }
    if (lo < kV && hi == kV) off[kV] = acc;
}

__global__ void fill_kernel(const int* __restrict__ faces,
                            const int* __restrict__ off,
                            int* __restrict__ cursor,
                            int* __restrict__ entries) {
    int f = blockIdx.x * blockDim.x + threadIdx.x;
    if (f >= kF) return;
#pragma unroll
    for (int k = 0; k < 3; ++k) {
        int v = faces[f * 3 + k];
        int p = atomicAdd(&cursor[v], 1);
        entries[off[v] + p] = f;
    }
}

// ---------------------------------------------------------------------------
// Kernel 1: per-batch joint transform chain.
// ---------------------------------------------------------------------------
__global__ void jt_kernel(const float* __restrict__ pose,
                          const float* __restrict__ jr,
                          float* __restrict__ A) {
    int b = threadIdx.x;
    if (b >= kB) return;

    float Gr[9], Gt[3];
    for (int j = 0; j < kJ; ++j) {
        float ax = pose[b * (kJ * 3) + j * 3 + 0];
        float ay = pose[b * (kJ * 3) + j * 3 + 1];
        float az = pose[b * (kJ * 3) + j * 3 + 2];
        float t2 = ax * ax + ay * ay + az * az + 1e-12f;
        float th = sqrtf(t2);
        float inv = 1.0f / th;
        float ux = ax * inv, uy = ay * inv, uz = az * inv;
        float s = sinf(th), c = cosf(th), oc = 1.0f - c;
        float R[9];
        R[0] = 1.0f + oc * (-(uy * uy + uz * uz));
        R[1] = -s * uz + oc * (ux * uy);
        R[2] =  s * uy + oc * (ux * uz);
        R[3] =  s * uz + oc * (ux * uy);
        R[4] = 1.0f + oc * (-(ux * ux + uz * uz));
        R[5] = -s * ux + oc * (uy * uz);
        R[6] = -s * uy + oc * (ux * uz);
        R[7] =  s * ux + oc * (uy * uz);
        R[8] = 1.0f + oc * (-(ux * ux + uy * uy));

        float jx = jr[j * 3 + 0], jy = jr[j * 3 + 1], jz = jr[j * 3 + 2];

        if (j == 0) {
            for (int k = 0; k < 9; ++k) Gr[k] = R[k];
            Gt[0] = jx; Gt[1] = jy; Gt[2] = jz;
        } else {
            float pjx = jr[(j - 1) * 3 + 0];
            float pjy = jr[(j - 1) * 3 + 1];
            float pjz = jr[(j - 1) * 3 + 2];
            float ltx = jx - pjx, lty = jy - pjy, ltz = jz - pjz;
            float nR[9], nT[3];
            for (int r = 0; r < 3; ++r) {
                float g0 = Gr[r * 3 + 0], g1 = Gr[r * 3 + 1], g2 = Gr[r * 3 + 2];
                nR[r * 3 + 0] = g0 * R[0] + g1 * R[3] + g2 * R[6];
                nR[r * 3 + 1] = g0 * R[1] + g1 * R[4] + g2 * R[7];
                nR[r * 3 + 2] = g0 * R[2] + g1 * R[5] + g2 * R[8];
                nT[r] = g0 * ltx + g1 * lty + g2 * ltz + Gt[r];
            }
            for (int k = 0; k < 9; ++k) Gr[k] = nR[k];
            Gt[0] = nT[0]; Gt[1] = nT[1]; Gt[2] = nT[2];
        }

        float tgx = Gt[0] - (Gr[0] * jx + Gr[1] * jy + Gr[2] * jz);
        float tgy = Gt[1] - (Gr[3] * jx + Gr[4] * jy + Gr[5] * jz);
        float tgz = Gt[2] - (Gr[6] * jx + Gr[7] * jy + Gr[8] * jz);
        float* Ao = A + ((size_t)b * kJ + j) * 12;
        Ao[0] = Gr[0]; Ao[1] = Gr[1]; Ao[2]  = Gr[2]; Ao[3]  = tgx;
        Ao[4] = Gr[3]; Ao[5] = Gr[4]; Ao[6]  = Gr[5]; Ao[7]  = tgy;
        Ao[8] = Gr[6]; Ao[9] = Gr[7]; Ao[10] = Gr[8]; Ao[11] = tgz;
    }
}

// ---------------------------------------------------------------------------
// Kernel 2: LBS skinning. VS = element stride of Vw (3 scalar / 4 = float4).
// ---------------------------------------------------------------------------
template <int VS>
__global__ void skin_kernel(const float* __restrict__ A,
                            const float* __restrict__ sw,
                            const float* __restrict__ vt,
                            const float* __restrict__ scale,
                            const float* __restrict__ trans,
                            float* __restrict__ Vw) {
    int b = blockIdx.y;
    int v = blockIdx.x * blockDim.x + threadIdx.x;
    __shared__ float sA[kJ * 12];
    if (threadIdx.x < kJ * 12) sA[threadIdx.x] = A[(size_t)b * kJ * 12 + threadIdx.x];
    __syncthreads();
    if (v >= kV) return;

    // 20 weights = 5 aligned float4 loads (v*20*4B is 16B-multiple)
    const float4* sw4 = (const float4*)(sw + (size_t)v * kJ);
    float w[kJ];
#pragma unroll
    for (int q = 0; q < 5; ++q) {
        float4 f = sw4[q];
        w[q * 4 + 0] = f.x; w[q * 4 + 1] = f.y;
        w[q * 4 + 2] = f.z; w[q * 4 + 3] = f.w;
    }

    float T[12];
#pragma unroll
    for (int k = 0; k < 12; ++k) T[k] = 0.0f;
#pragma unroll
    for (int j = 0; j < kJ; ++j) {
        float wj = w[j];
#pragma unroll
        for (int k = 0; k < 12; ++k) T[k] += wj * sA[j * 12 + k];
    }
    float x = vt[v * 3 + 0], y = vt[v * 3 + 1], z = vt[v * 3 + 2];
    float px = T[0] * x + T[1] * y + T[2]  * z + T[3];
    float py = T[4] * x + T[5] * y + T[6]  * z + T[7];
    float pz = T[8] * x + T[9] * y + T[10] * z + T[11];
    float s = scale[b];
    float tx = trans[b * 3 + 0], ty = trans[b * 3 + 1], tz = trans[b * 3 + 2];
    size_t o = ((size_t)b * kV + v) * VS;
    if (VS == 4) {
        *(float4*)(Vw + o) = make_float4(px * s + tx, py * s + ty, pz * s + tz, 0.0f);
    } else {
        Vw[o + 0] = px * s + tx;
        Vw[o + 1] = py * s + ty;
        Vw[o + 2] = pz * s + tz;
    }
}

// ---------------------------------------------------------------------------
// Kernel 3a (fast): per-(b,f) face normals -> dense float4 buffer.
// ---------------------------------------------------------------------------
__global__ void fnorm4_kernel(const float* __restrict__ Vw,
                              const int* __restrict__ faces,
                              float* __restrict__ fn) {
    int b = blockIdx.y;
    int f = blockIdx.x * blockDim.x + threadIdx.x;
    if (f >= kF) return;
    int i0 = faces[f * 3 + 0];
    int i1 = faces[f * 3 + 1];
    int i2 = faces[f * 3 + 2];
    const float* base = Vw + (size_t)b * kV * 4;
    float4 a = *(const float4*)(base + (size_t)i0 * 4);
    float4 c1 = *(const float4*)(base + (size_t)i1 * 4);
    float4 c2 = *(const float4*)(base + (size_t)i2 * 4);
    float e1x = c1.x - a.x, e1y = c1.y - a.y, e1z = c1.z - a.z;
    float e2x = c2.x - a.x, e2y = c2.y - a.y, e2z = c2.z - a.z;
    float4 o = make_float4(e1y * e2z - e1z * e2y,
                           e1z * e2x - e1x * e2z,
                           e1x * e2y - e1y * e2x, 0.0f);
    *(float4*)(fn + ((size_t)b * kF + f) * 4) = o;
}

// ---------------------------------------------------------------------------
// Kernel 3b (fast): per-(b,v) sum of adjacent face normals (1-hop gather).
// ---------------------------------------------------------------------------
__global__ void gather_fn_kernel(const float* __restrict__ fn,
                                 const int* __restrict__ off,
                                 const int* __restrict__ entries,
                                 float* __restrict__ nrm) {
    int b = blockIdx.y;
    int v = blockIdx.x * blockDim.x + threadIdx.x;
    if (v >= kV) return;
    const float* fb = fn + (size_t)b * kF * 4;
    float sx = 0.0f, sy = 0.0f, sz = 0.0f;
    int e0 = off[v], e1 = off[v + 1];
    for (int e = e0; e < e1; ++e) {
        int f = entries[e];
        float4 t = *(const float4*)(fb + (size_t)f * 4);
        sx += t.x; sy += t.y; sz += t.z;
    }
    *(float4*)(nrm + ((size_t)b * kV + v) * 4) = make_float4(sx, sy, sz, 0.0f);
}

// ---------------------------------------------------------------------------
// Kernel 3 (fallback): R2's recompute-gather, stride-3 buffers.
// ---------------------------------------------------------------------------
__global__ void gather_recompute_kernel(const float* __restrict__ Vw,
                                        const int* __restrict__ faces,
                                        const int* __restrict__ off,
                                        const int* __restrict__ entries,
                                        float* __restrict__ nrm) {
    int b = blockIdx.y;
    int v = blockIdx.x * blockDim.x + threadIdx.x;
    if (v >= kV) return;
    const float* base = Vw + (size_t)b * kV * 3;
    float sx = 0.0f, sy = 0.0f, sz = 0.0f;
    int e0 = off[v], e1 = off[v + 1];
    for (int e = e0; e < e1; ++e) {
        int f = entries[e];
        int i0 = faces[f * 3 + 0];
        int i1 = faces[f * 3 + 1];
        int i2 = faces[f * 3 + 2];
        float ax = base[i0 * 3 + 0], ay = base[i0 * 3 + 1], az = base[i0 * 3 + 2];
        float bx = base[i1 * 3 + 0], by = base[i1 * 3 + 1], bz = base[i1 * 3 + 2];
        float cx = base[i2 * 3 + 0], cy = base[i2 * 3 + 1], cz = base[i2 * 3 + 2];
        float e1x = bx - ax, e1y = by - ay, e1z = bz - az;
        float e2x = cx - ax, e2y = cy - ay, e2z = cz - az;
        sx += e1y * e2z - e1z * e2y;
        sy += e1z * e2x - e1x * e2z;
        sz += e1x * e2y - e1y * e2x;
    }
    size_t o = ((size_t)b * kV + v) * 3;
    nrm[o + 0] = sx;
    nrm[o + 1] = sy;
    nrm[o + 2] = sz;
}

// ---------------------------------------------------------------------------
// Kernel 4: finalize per (b, n). VS = stride of Vw/nrm.
// ---------------------------------------------------------------------------
template <int VS>
__global__ void finalize_kernel(const float* __restrict__ Vw,
                                const float* __restrict__ nrm,
                                const int* __restrict__ vidx,
                                const float* __restrict__ poff,
                                const float* __restrict__ craw,
                                const float* __restrict__ oraw,
                                const float* __restrict__ lsc,
                                const float* __restrict__ quat,
                                float* __restrict__ out) {
    int b = blockIdx.y;
    int n = blockIdx.x * blockDim.x + threadIdx.x;
    if (n >= kN) return;

    int vi = vidx[n];
    size_t vo = ((size_t)b * kV + vi) * VS;
    float bx, by, bz, nx0, ny0, nz0;
    if (VS == 4) {
        float4 bt4 = *(const float4*)(Vw + vo);
        float4 nt4 = *(const float4*)(nrm + vo);
        bx = bt4.x; by = bt4.y; bz = bt4.z;
        nx0 = nt4.x; ny0 = nt4.y; nz0 = nt4.z;
    } else {
        bx = Vw[vo + 0]; by = Vw[vo + 1]; bz = Vw[vo + 2];
        nx0 = nrm[vo + 0]; ny0 = nrm[vo + 1]; nz0 = nrm[vo + 2];
    }

    float ninv = rsqrtf(nx0 * nx0 + ny0 * ny0 + nz0 * nz0 + 1e-12f);
    float nx = nx0 * ninv, ny = ny0 * ninv, nz = nz0 * ninv;

    bool small = fabsf(nx) < 0.9f;
    float refx = small ? 1.0f : 0.0f;
    float refz = small ? 0.0f : 1.0f;
    float d = refx * nx + refz * nz;
    float tx0 = refx - d * nx, ty0 = -d * ny, tz0 = refz - d * nz;
    float tinv = rsqrtf(tx0 * tx0 + ty0 * ty0 + tz0 * tz0 + 1e-12f);
    float tx = tx0 * tinv, ty = ty0 * tinv, tz = tz0 * tinv;

    float btx = ny * tz - nz * ty;
    float bty = nz * tx - nx * tz;
    float btz = nx * ty - ny * tx;

    float o0 = poff[n * 3 + 0], o1 = poff[n * 3 + 1], o2 = poff[n * 3 + 2];
    float mx = bx + o0 * tx + o1 * btx + o2 * nx;
    float my = by + o0 * ty + o1 * bty + o2 * ny;
    float mz = bz + o0 * tz + o1 * btz + o2 * nz;

    float r00 = tx, r01 = btx, r02 = nx;
    float r10 = ty, r11 = bty, r12 = ny;
    float r20 = tz, r21 = btz, r22 = nz;
    float tr = r00 + r11 + r22;
    float q0, q1, q2, q3;
    if (tr > 0.0f) {
        float s = sqrtf(fmaxf(tr + 1.0f, kEps)) * 2.0f;
        q0 = 0.25f * s;
        q1 = (r21 - r12) / s;
        q2 = (r02 - r20) / s;
        q3 = (r10 - r01) / s;
    } else if (r00 > r11 && r00 > r22) {
        float s = sqrtf(fmaxf(1.0f + r00 - r11 - r22, kEps)) * 2.0f;
        q0 = (r21 - r12) / s;
        q1 = 0.25f * s;
        q2 = (r01 + r10) / s;
        q3 = (r02 + r20) / s;
    } else if (r11 > r22) {
        float s = sqrtf(fmaxf(1.0f + r11 - r00 - r22, kEps)) * 2.0f;
        q0 = (r02 - r20) / s;
        q1 = (r01 + r10) / s;
        q2 = 0.25f * s;
        q3 = (r12 + r21) / s;
    } else {
        float s = sqrtf(fmaxf(1.0f + r22 - r00 - r11, kEps)) * 2.0f;
        q0 = (r10 - r01) / s;
        q1 = (r02 + r20) / s;
        q2 = (r12 + r21) / s;
        q3 = 0.25f * s;
    }
    float qinv = rsqrtf(q0 * q0 + q1 * q1 + q2 * q2 + q3 * q3 + 1e-12f);
    q0 *= qinv; q1 *= qinv; q2 *= qinv; q3 *= qinv;

    float4 lq = *(const float4*)(quat + (size_t)n * 4);
    float lw = lq.x, lx = lq.y, ly = lq.z, lz = lq.w;
    float linv = rsqrtf(lw * lw + lx * lx + ly * ly + lz * lz + 1e-12f);
    lw *= linv; lx *= linv; ly *= linv; lz *= linv;

    float rw = q0 * lw - q1 * lx - q2 * ly - q3 * lz;
    float rx = q0 * lx + q1 * lw + q2 * lz - q3 * ly;
    float ry = q0 * ly - q1 * lz + q2 * lw + q3 * lx;
    float rz = q0 * lz + q1 * ly - q2 * lx + q3 * lw;

    float c0 = 1.0f / (1.0f + __expf(-craw[n * 3 + 0]));
    float c1 = 1.0f / (1.0f + __expf(-craw[n * 3 + 1]));
    float c2 = 1.0f / (1.0f + __expf(-craw[n * 3 + 2]));
    float op = 1.0f / (1.0f + __expf(-oraw[n]));
    float s0 = fminf(fmaxf(__expf(lsc[n * 3 + 0]), 0.0005f), 0.05f);
    float s1 = fminf(fmaxf(__expf(lsc[n * 3 + 1]), 0.0005f), 0.05f);
    float s2 = fminf(fmaxf(__expf(lsc[n * 3 + 2]), 0.0005f), 0.05f);

    size_t bn = (size_t)b * kN + n;
    out[OFF_MEANS + bn * 3 + 0] = mx;
    out[OFF_MEANS + bn * 3 + 1] = my;
    out[OFF_MEANS + bn * 3 + 2] = mz;
    out[OFF_COLORS + bn * 3 + 0] = c0;
    out[OFF_COLORS + bn * 3 + 1] = c1;
    out[OFF_COLORS + bn * 3 + 2] = c2;
    out[OFF_OPAC + bn] = op;
    out[OFF_SCALE + bn * 3 + 0] = s0;
    out[OFF_SCALE + bn * 3 + 1] = s1;
    out[OFF_SCALE + bn * 3 + 2] = s2;
    *(float4*)(out + OFF_ROT + bn * 4) = make_float4(rw, rx, ry, rz);
}

extern "C" void kernel_launch(void* const* d_in, const int* in_sizes, int n_in,
                              void* d_out, int out_size, void* d_ws, size_t ws_size,
                              hipStream_t stream) {
    const float* pose  = (const float*)d_in[0];
    const float* trans = (const float*)d_in[1];
    const float* scale = (const float*)d_in[2];
    const float* vt    = (const float*)d_in[3];
    const float* sw    = (const float*)d_in[4];
    const float* jr    = (const float*)d_in[5];
    const float* poff  = (const float*)d_in[6];
    const float* craw  = (const float*)d_in[7];
    const float* oraw  = (const float*)d_in[8];
    const float* lsc   = (const float*)d_in[9];
    const float* quat  = (const float*)d_in[10];
    const int*   vidx  = (const int*)d_in[11];
    const int*   faces = (const int*)d_in[12];
    float* out = (float*)d_out;
    char* ws = (char*)d_ws;

    const bool fast = (ws_size >= FWS_END);

    dim3 gV((kV + 255) / 256, kB);
    dim3 gF((kF + 255) / 256, kB);
    dim3 gN((kN + 255) / 256, kB);

    if (fast) {
        float* A       = (float*)(ws + FWS_A);
        float* Vw      = (float*)(ws + FWS_VW);
        float* fn      = (float*)(ws + FWS_FN);
        float* nrm     = (float*)(ws + FWS_NRM);
        int*   cnt     = (int*)(ws + FWS_CNT);
        int*   offs    = (int*)(ws + FWS_OFFS);
        int*   entries = (int*)(ws + FWS_ENTRIES);

        hipMemsetAsync(cnt, 0, kV * sizeof(int), stream);
        count_kernel<<<(kF + 255) / 256, 256, 0, stream>>>(faces, cnt);
        scan_kernel<<<1, 1024, 0, stream>>>(cnt, offs);
        hipMemsetAsync(cnt, 0, kV * sizeof(int), stream);
        fill_kernel<<<(kF + 255) / 256, 256, 0, stream>>>(faces, offs, cnt, entries);

        jt_kernel<<<1, 64, 0, stream>>>(pose, jr, A);
        skin_kernel<4><<<gV, 256, 0, stream>>>(A, sw, vt, scale, trans, Vw);
        fnorm4_kernel<<<gF, 256, 0, stream>>>(Vw, faces, fn);
        gather_fn_kernel<<<gV, 256, 0, stream>>>(fn, offs, entries, nrm);
        finalize_kernel<4><<<gN, 256, 0, stream>>>(Vw, nrm, vidx, poff, craw,
                                                   oraw, lsc, quat, out);
    } else {
        float* A       = (float*)(ws + SWS_A);
        float* Vw      = (float*)(ws + SWS_VW);
        float* nrm     = (float*)(ws + SWS_NRM);
        int*   cnt     = (int*)(ws + SWS_CNT);
        int*   offs    = (int*)(ws + SWS_OFFS);
        int*   entries = (int*)(ws + SWS_ENTRIES);

        hipMemsetAsync(cnt, 0, kV * sizeof(int), stream);
        count_kernel<<<(kF + 255) / 256, 256, 0, stream>>>(faces, cnt);
        scan_kernel<<<1, 1024, 0, stream>>>(cnt, offs);
        hipMemsetAsync(cnt, 0, kV * sizeof(int), stream);
        fill_kernel<<<(kF + 255) / 256, 256, 0, stream>>>(faces, offs, cnt, entries);

        jt_kernel<<<1, 64, 0, stream>>>(pose, jr, A);
        skin_kernel<3><<<gV, 256, 0, stream>>>(A, sw, vt, scale, trans, Vw);
        gather_recompute_kernel<<<gV, 256, 0, stream>>>(Vw, faces, offs, entries, nrm);
        finalize_kernel<3><<<gN, 256, 0, stream>>>(Vw, nrm, vidx, poff, craw,
                                                   oraw, lsc, quat, out);
    }
}

// Round 4
// 326.811 us; speedup vs baseline: 1.0234x; 1.0234x over previous
//
#include <hip/hip_runtime.h>
#include <math.h>

// GaussianAvatar: LBS skinning + tangent frames + gaussian param finalize.
// R4: intermediates (Vw, nrm) live inside d_out regions that are overwritten
// later (opac/scale), so the workspace only holds the CSR structures (~2.7MB,
// guaranteed fit — R3's 52MB fast path never ran). Gather uses int4 triangle
// records (one indirection removed), finalize is split into a gather pass
// (means+rot) and a pure-streaming broadcast pass (colors+opac+scale).
namespace {
constexpr int kB = 32;
constexpr int kV = 25000;
constexpr int kJ = 20;
constexpr int kF = 50000;
constexpr int kN = 200000;

constexpr float kEps = 1e-8f;

// output layout (flat float32, concatenated in return order)
constexpr size_t OFF_MEANS  = 0;
constexpr size_t OFF_COLORS = (size_t)kB * kN * 3;              // 19,200,000
constexpr size_t OFF_OPAC   = OFF_COLORS + (size_t)kB * kN * 3; // 38,400,000
constexpr size_t OFF_SCALE  = OFF_OPAC + (size_t)kB * kN;       // 44,800,000
constexpr size_t OFF_ROT    = OFF_SCALE + (size_t)kB * kN * 3;  // 64,000,000

// scratch-in-output (element offsets, float4-strided per vertex):
//   Vw  -> opac region  (needs B*V*4 = 3.2M floats; region has 6.4M)
//   nrm -> scale region (needs B*V*4 = 3.2M floats; region has 19.2M)
// passA (means+rot) reads opac/scale regions, writes means/rot: disjoint.
// passB (colors+opac+scale) runs last and overwrites the dead scratch.

// workspace layout (bytes)
constexpr size_t WS_A    = 0;          // B*J*12 floats = 30,720
constexpr size_t WS_CNT  = 32768;      // V ints
constexpr size_t WS_OFFS = 132800;     // V+1 ints
constexpr size_t WS_TRI  = 232848;     // 3F int4 = 2,400,000 B (16B aligned)
// end ~ 2.64 MB
}

// ---------------------------------------------------------------------------
// CSR build: count, scan (one block), fill triangle records.
// ---------------------------------------------------------------------------
__global__ void count_kernel(const int* __restrict__ faces,
                             int* __restrict__ cnt) {
    int f = blockIdx.x * blockDim.x + threadIdx.x;
    if (f >= kF) return;
    atomicAdd(&cnt[faces[f * 3 + 0]], 1);
    atomicAdd(&cnt[faces[f * 3 + 1]], 1);
    atomicAdd(&cnt[faces[f * 3 + 2]], 1);
}

__global__ void scan_kernel(const int* __restrict__ cnt,
                            int* __restrict__ off) {
    __shared__ int partial[1024];
    int t = threadIdx.x;
    int lo = t * 25;
    int hi = min(lo + 25, kV);
    int s = 0;
    for (int i = lo; i < hi; ++i) s += cnt[i];
    partial[t] = s;
    __syncthreads();
    if (t == 0) {
        int acc = 0;
        for (int i = 0; i < 1024; ++i) {
            int v = partial[i];
            partial[i] = acc;
            acc += v;
        }
    }
    __syncthreads();
    int acc = partial[t];
    for (int i = lo; i < hi; ++i) {
        off[i] = acc;
        acc += cnt[i];
    }
    if (lo < kV && hi == kV) off[kV] = acc;
}

// Each CSR entry stores the full triangle (i0,i1,i2) -> gather needs no
// faces[] indirection.
__global__ void fill_tri_kernel(const int* __restrict__ faces,
                                const int* __restrict__ off,
                                int* __restrict__ cursor,
                                int4* __restrict__ tri) {
    int f = blockIdx.x * blockDim.x + threadIdx.x;
    if (f >= kF) return;
    int i0 = faces[f * 3 + 0];
    int i1 = faces[f * 3 + 1];
    int i2 = faces[f * 3 + 2];
    int4 rec = make_int4(i0, i1, i2, 0);
#pragma unroll
    for (int k = 0; k < 3; ++k) {
        int v = (k == 0) ? i0 : (k == 1) ? i1 : i2;
        int p = atomicAdd(&cursor[v], 1);
        tri[off[v] + p] = rec;
    }
}

// ---------------------------------------------------------------------------
// Kernel 1: per-batch joint transform chain.
// ---------------------------------------------------------------------------
__global__ void jt_kernel(const float* __restrict__ pose,
                          const float* __restrict__ jr,
                          float* __restrict__ A) {
    int b = threadIdx.x;
    if (b >= kB) return;

    float Gr[9], Gt[3];
    for (int j = 0; j < kJ; ++j) {
        float ax = pose[b * (kJ * 3) + j * 3 + 0];
        float ay = pose[b * (kJ * 3) + j * 3 + 1];
        float az = pose[b * (kJ * 3) + j * 3 + 2];
        float t2 = ax * ax + ay * ay + az * az + 1e-12f;
        float th = sqrtf(t2);
        float inv = 1.0f / th;
        float ux = ax * inv, uy = ay * inv, uz = az * inv;
        float s = sinf(th), c = cosf(th), oc = 1.0f - c;
        float R[9];
        R[0] = 1.0f + oc * (-(uy * uy + uz * uz));
        R[1] = -s * uz + oc * (ux * uy);
        R[2] =  s * uy + oc * (ux * uz);
        R[3] =  s * uz + oc * (ux * uy);
        R[4] = 1.0f + oc * (-(ux * ux + uz * uz));
        R[5] = -s * ux + oc * (uy * uz);
        R[6] = -s * uy + oc * (ux * uz);
        R[7] =  s * ux + oc * (uy * uz);
        R[8] = 1.0f + oc * (-(ux * ux + uy * uy));

        float jx = jr[j * 3 + 0], jy = jr[j * 3 + 1], jz = jr[j * 3 + 2];

        if (j == 0) {
            for (int k = 0; k < 9; ++k) Gr[k] = R[k];
            Gt[0] = jx; Gt[1] = jy; Gt[2] = jz;
        } else {
            float pjx = jr[(j - 1) * 3 + 0];
            float pjy = jr[(j - 1) * 3 + 1];
            float pjz = jr[(j - 1) * 3 + 2];
            float ltx = jx - pjx, lty = jy - pjy, ltz = jz - pjz;
            float nR[9], nT[3];
            for (int r = 0; r < 3; ++r) {
                float g0 = Gr[r * 3 + 0], g1 = Gr[r * 3 + 1], g2 = Gr[r * 3 + 2];
                nR[r * 3 + 0] = g0 * R[0] + g1 * R[3] + g2 * R[6];
                nR[r * 3 + 1] = g0 * R[1] + g1 * R[4] + g2 * R[7];
                nR[r * 3 + 2] = g0 * R[2] + g1 * R[5] + g2 * R[8];
                nT[r] = g0 * ltx + g1 * lty + g2 * ltz + Gt[r];
            }
            for (int k = 0; k < 9; ++k) Gr[k] = nR[k];
            Gt[0] = nT[0]; Gt[1] = nT[1]; Gt[2] = nT[2];
        }

        float tgx = Gt[0] - (Gr[0] * jx + Gr[1] * jy + Gr[2] * jz);
        float tgy = Gt[1] - (Gr[3] * jx + Gr[4] * jy + Gr[5] * jz);
        float tgz = Gt[2] - (Gr[6] * jx + Gr[7] * jy + Gr[8] * jz);
        float* Ao = A + ((size_t)b * kJ + j) * 12;
        Ao[0] = Gr[0]; Ao[1] = Gr[1]; Ao[2]  = Gr[2]; Ao[3]  = tgx;
        Ao[4] = Gr[3]; Ao[5] = Gr[4]; Ao[6]  = Gr[5]; Ao[7]  = tgy;
        Ao[8] = Gr[6]; Ao[9] = Gr[7]; Ao[10] = Gr[8]; Ao[11] = tgz;
    }
}

// ---------------------------------------------------------------------------
// Kernel 2: LBS skinning -> float4 Vw (lives in the opac output region).
// ---------------------------------------------------------------------------
__global__ void skin_kernel(const float* __restrict__ A,
                            const float* __restrict__ sw,
                            const float* __restrict__ vt,
                            const float* __restrict__ scale,
                            const float* __restrict__ trans,
                            float4* __restrict__ Vw) {
    int b = blockIdx.y;
    int v = blockIdx.x * blockDim.x + threadIdx.x;
    __shared__ float sA[kJ * 12];
    if (threadIdx.x < kJ * 12) sA[threadIdx.x] = A[(size_t)b * kJ * 12 + threadIdx.x];
    __syncthreads();
    if (v >= kV) return;

    const float4* sw4 = (const float4*)(sw + (size_t)v * kJ);
    float w[kJ];
#pragma unroll
    for (int q = 0; q < 5; ++q) {
        float4 f = sw4[q];
        w[q * 4 + 0] = f.x; w[q * 4 + 1] = f.y;
        w[q * 4 + 2] = f.z; w[q * 4 + 3] = f.w;
    }

    float T[12];
#pragma unroll
    for (int k = 0; k < 12; ++k) T[k] = 0.0f;
#pragma unroll
    for (int j = 0; j < kJ; ++j) {
        float wj = w[j];
#pragma unroll
        for (int k = 0; k < 12; ++k) T[k] += wj * sA[j * 12 + k];
    }
    float x = vt[v * 3 + 0], y = vt[v * 3 + 1], z = vt[v * 3 + 2];
    float px = T[0] * x + T[1] * y + T[2]  * z + T[3];
    float py = T[4] * x + T[5] * y + T[6]  * z + T[7];
    float pz = T[8] * x + T[9] * y + T[10] * z + T[11];
    float s = scale[b];
    float tx = trans[b * 3 + 0], ty = trans[b * 3 + 1], tz = trans[b * 3 + 2];
    Vw[(size_t)b * kV + v] = make_float4(px * s + tx, py * s + ty, pz * s + tz, 0.0f);
}

// ---------------------------------------------------------------------------
// Kernel 3: per-(b,v) normal sum via triangle records. 1 int4 + 3 float4
// L2-resident loads per adjacent face; no faces[] indirection, no atomics.
// nrm lives in the scale output region.
// ---------------------------------------------------------------------------
__global__ void gather_tri_kernel(const float4* __restrict__ Vw,
                                  const int* __restrict__ off,
                                  const int4* __restrict__ tri,
                                  float4* __restrict__ nrm) {
    int b = blockIdx.y;
    int v = blockIdx.x * blockDim.x + threadIdx.x;
    if (v >= kV) return;
    const float4* base = Vw + (size_t)b * kV;
    float sx = 0.0f, sy = 0.0f, sz = 0.0f;
    int e0 = off[v], e1 = off[v + 1];
    for (int e = e0; e < e1; ++e) {
        int4 t = tri[e];
        float4 a  = base[t.x];
        float4 c1 = base[t.y];
        float4 c2 = base[t.z];
        float e1x = c1.x - a.x, e1y = c1.y - a.y, e1z = c1.z - a.z;
        float e2x = c2.x - a.x, e2y = c2.y - a.y, e2z = c2.z - a.z;
        sx += e1y * e2z - e1z * e2y;
        sy += e1z * e2x - e1x * e2z;
        sz += e1x * e2y - e1y * e2x;
    }
    nrm[(size_t)b * kV + v] = make_float4(sx, sy, sz, 0.0f);
}

// ---------------------------------------------------------------------------
// Kernel 4a (passA): means + rotations. Reads Vw (opac region) and nrm
// (scale region); writes means + rot regions only.
// ---------------------------------------------------------------------------
__global__ void finalize_mr_kernel(const float4* __restrict__ Vw,
                                   const float4* __restrict__ nrm,
                                   const int* __restrict__ vidx,
                                   const float* __restrict__ poff,
                                   const float* __restrict__ quat,
                                   float* __restrict__ out) {
    int b = blockIdx.y;
    int n = blockIdx.x * blockDim.x + threadIdx.x;
    if (n >= kN) return;

    int vi = vidx[n];
    size_t vo = (size_t)b * kV + vi;
    float4 bt4 = Vw[vo];
    float4 nt4 = nrm[vo];
    float bx = bt4.x, by = bt4.y, bz = bt4.z;
    float nx0 = nt4.x, ny0 = nt4.y, nz0 = nt4.z;

    float ninv = rsqrtf(nx0 * nx0 + ny0 * ny0 + nz0 * nz0 + 1e-12f);
    float nx = nx0 * ninv, ny = ny0 * ninv, nz = nz0 * ninv;

    bool small = fabsf(nx) < 0.9f;
    float refx = small ? 1.0f : 0.0f;
    float refz = small ? 0.0f : 1.0f;
    float d = refx * nx + refz * nz;
    float tx0 = refx - d * nx, ty0 = -d * ny, tz0 = refz - d * nz;
    float tinv = rsqrtf(tx0 * tx0 + ty0 * ty0 + tz0 * tz0 + 1e-12f);
    float tx = tx0 * tinv, ty = ty0 * tinv, tz = tz0 * tinv;

    float btx = ny * tz - nz * ty;
    float bty = nz * tx - nx * tz;
    float btz = nx * ty - ny * tx;

    float o0 = poff[n * 3 + 0], o1 = poff[n * 3 + 1], o2 = poff[n * 3 + 2];
    float mx = bx + o0 * tx + o1 * btx + o2 * nx;
    float my = by + o0 * ty + o1 * bty + o2 * ny;
    float mz = bz + o0 * tz + o1 * btz + o2 * nz;

    float r00 = tx, r01 = btx, r02 = nx;
    float r10 = ty, r11 = bty, r12 = ny;
    float r20 = tz, r21 = btz, r22 = nz;
    float tr = r00 + r11 + r22;
    float q0, q1, q2, q3;
    if (tr > 0.0f) {
        float s = sqrtf(fmaxf(tr + 1.0f, kEps)) * 2.0f;
        q0 = 0.25f * s;
        q1 = (r21 - r12) / s;
        q2 = (r02 - r20) / s;
        q3 = (r10 - r01) / s;
    } else if (r00 > r11 && r00 > r22) {
        float s = sqrtf(fmaxf(1.0f + r00 - r11 - r22, kEps)) * 2.0f;
        q0 = (r21 - r12) / s;
        q1 = 0.25f * s;
        q2 = (r01 + r10) / s;
        q3 = (r02 + r20) / s;
    } else if (r11 > r22) {
        float s = sqrtf(fmaxf(1.0f + r11 - r00 - r22, kEps)) * 2.0f;
        q0 = (r02 - r20) / s;
        q1 = (r01 + r10) / s;
        q2 = 0.25f * s;
        q3 = (r12 + r21) / s;
    } else {
        float s = sqrtf(fmaxf(1.0f + r22 - r00 - r11, kEps)) * 2.0f;
        q0 = (r10 - r01) / s;
        q1 = (r02 + r20) / s;
        q2 = (r12 + r21) / s;
        q3 = 0.25f * s;
    }
    float qinv = rsqrtf(q0 * q0 + q1 * q1 + q2 * q2 + q3 * q3 + 1e-12f);
    q0 *= qinv; q1 *= qinv; q2 *= qinv; q3 *= qinv;

    float4 lq = *(const float4*)(quat + (size_t)n * 4);
    float lw = lq.x, lx = lq.y, ly = lq.z, lz = lq.w;
    float linv = rsqrtf(lw * lw + lx * lx + ly * ly + lz * lz + 1e-12f);
    lw *= linv; lx *= linv; ly *= linv; lz *= linv;

    float rw = q0 * lw - q1 * lx - q2 * ly - q3 * lz;
    float rx = q0 * lx + q1 * lw + q2 * lz - q3 * ly;
    float ry = q0 * ly - q1 * lz + q2 * lw + q3 * lx;
    float rz = q0 * lz + q1 * ly - q2 * lx + q3 * lw;

    size_t bn = (size_t)b * kN + n;
    out[OFF_MEANS + bn * 3 + 0] = mx;
    out[OFF_MEANS + bn * 3 + 1] = my;
    out[OFF_MEANS + bn * 3 + 2] = mz;
    *(float4*)(out + OFF_ROT + bn * 4) = make_float4(rw, rx, ry, rz);
}

// ---------------------------------------------------------------------------
// Kernel 4b (passB): colors + opacity + scales (b-independent values,
// broadcast with pure float4 stores; 4 gaussians per thread). Runs LAST —
// overwrites the Vw/nrm scratch living in opac/scale.
// ---------------------------------------------------------------------------
__device__ __forceinline__ float sigm(float x) {
    return 1.0f / (1.0f + __expf(-x));
}
__device__ __forceinline__ float eclip(float x) {
    return fminf(fmaxf(__expf(x), 0.0005f), 0.05f);
}

__global__ void finalize_cos_kernel(const float* __restrict__ craw,
                                    const float* __restrict__ oraw,
                                    const float* __restrict__ lsc,
                                    float* __restrict__ out) {
    int b = blockIdx.y;
    int q = blockIdx.x * blockDim.x + threadIdx.x;  // unit of 4 gaussians
    if (q >= kN / 4) return;
    int n0 = q * 4;

    const float4* cr4 = (const float4*)(craw + (size_t)n0 * 3);
    float4 ca = cr4[0], cb = cr4[1], cc = cr4[2];
    float4 ov = *(const float4*)(oraw + n0);
    const float4* ls4 = (const float4*)(lsc + (size_t)n0 * 3);
    float4 la = ls4[0], lb = ls4[1], lc = ls4[2];

    float4 sa = make_float4(sigm(ca.x), sigm(ca.y), sigm(ca.z), sigm(ca.w));
    float4 sb = make_float4(sigm(cb.x), sigm(cb.y), sigm(cb.z), sigm(cb.w));
    float4 sc = make_float4(sigm(cc.x), sigm(cc.y), sigm(cc.z), sigm(cc.w));
    float4 so = make_float4(sigm(ov.x), sigm(ov.y), sigm(ov.z), sigm(ov.w));
    float4 ea = make_float4(eclip(la.x), eclip(la.y), eclip(la.z), eclip(la.w));
    float4 eb = make_float4(eclip(lb.x), eclip(lb.y), eclip(lb.z), eclip(lb.w));
    float4 ec = make_float4(eclip(lc.x), eclip(lc.y), eclip(lc.z), eclip(lc.w));

    size_t bn0 = (size_t)b * kN + n0;
    float4* co = (float4*)(out + OFF_COLORS + bn0 * 3);
    co[0] = sa; co[1] = sb; co[2] = sc;
    *(float4*)(out + OFF_OPAC + bn0) = so;
    float4* sco = (float4*)(out + OFF_SCALE + bn0 * 3);
    sco[0] = ea; sco[1] = eb; sco[2] = ec;
}

extern "C" void kernel_launch(void* const* d_in, const int* in_sizes, int n_in,
                              void* d_out, int out_size, void* d_ws, size_t ws_size,
                              hipStream_t stream) {
    const float* pose  = (const float*)d_in[0];
    const float* trans = (const float*)d_in[1];
    const float* scale = (const float*)d_in[2];
    const float* vt    = (const float*)d_in[3];
    const float* sw    = (const float*)d_in[4];
    const float* jr    = (const float*)d_in[5];
    const float* poff  = (const float*)d_in[6];
    const float* craw  = (const float*)d_in[7];
    const float* oraw  = (const float*)d_in[8];
    const float* lsc   = (const float*)d_in[9];
    const float* quat  = (const float*)d_in[10];
    const int*   vidx  = (const int*)d_in[11];
    const int*   faces = (const int*)d_in[12];
    float* out = (float*)d_out;
    char* ws = (char*)d_ws;

    float* A    = (float*)(ws + WS_A);
    int*   cnt  = (int*)(ws + WS_CNT);
    int*   offs = (int*)(ws + WS_OFFS);
    int4*  tri  = (int4*)(ws + WS_TRI);

    // scratch inside d_out (overwritten by later kernels)
    float4* Vw  = (float4*)(out + OFF_OPAC);   // B*V float4 = 12.8 MB of 25.6
    float4* nrm = (float4*)(out + OFF_SCALE);  // B*V float4 = 12.8 MB of 76.8

    dim3 gV((kV + 255) / 256, kB);
    dim3 gN((kN + 255) / 256, kB);
    dim3 gQ((kN / 4 + 255) / 256, kB);

    // CSR adjacency (batch-independent)
    hipMemsetAsync(cnt, 0, kV * sizeof(int), stream);
    count_kernel<<<(kF + 255) / 256, 256, 0, stream>>>(faces, cnt);
    scan_kernel<<<1, 1024, 0, stream>>>(cnt, offs);
    hipMemsetAsync(cnt, 0, kV * sizeof(int), stream);
    fill_tri_kernel<<<(kF + 255) / 256, 256, 0, stream>>>(faces, offs, cnt, tri);

    // joints + skinning
    jt_kernel<<<1, 64, 0, stream>>>(pose, jr, A);
    skin_kernel<<<gV, 256, 0, stream>>>(A, sw, vt, scale, trans, Vw);

    // vertex normals
    gather_tri_kernel<<<gV, 256, 0, stream>>>(Vw, offs, tri, nrm);

    // passA: means + rotations (reads Vw/nrm scratch)
    finalize_mr_kernel<<<gN, 256, 0, stream>>>(Vw, nrm, vidx, poff, quat, out);

    // passB: colors + opacity + scales (overwrites scratch, runs last)
    finalize_cos_kernel<<<gQ, 256, 0, stream>>>(craw, oraw, lsc, out);
}

// Round 5
// 302.696 us; speedup vs baseline: 1.1050x; 1.0797x over previous
//
#include <hip/hip_runtime.h>
#include <math.h>

// GaussianAvatar R5:
//  - CSR scan removed: fixed-capacity slot-major buckets tri[slot][v] (CAP=40,
//    mean vertex degree 6; slot-major makes the per-vertex gather coalesced).
//  - Per-vertex frame+quat hoist: frame (n,t,bt) and its quaternion fq depend
//    only on (b, vertex). Computed once per (b,v) (N/V ~ 8x reuse) into a
//    packed 32B record {pos, fq} so finalize gathers ONE cache line per n.
//  - finalize_mr4: 4 gaussians/thread, all-float4 loads/stores, t/bt/n
//    reconstructed from fq (frame is orthonormal => R(fq)=frame to ~1e-6).
//  - Scratch lives in d_out regions overwritten later (rec->opac, Vw->scale).
namespace {
constexpr int kB = 32;
constexpr int kV = 25000;
constexpr int kJ = 20;
constexpr int kF = 50000;
constexpr int kN = 200000;
constexpr int kCap = 40;   // max tracked faces/vertex; Poisson(6) tail => safe

constexpr float kEps = 1e-8f;

// output layout (flat float32, concatenated in return order)
constexpr size_t OFF_MEANS  = 0;
constexpr size_t OFF_COLORS = (size_t)kB * kN * 3;              // 19,200,000
constexpr size_t OFF_OPAC   = OFF_COLORS + (size_t)kB * kN * 3; // 38,400,000
constexpr size_t OFF_SCALE  = OFF_OPAC + (size_t)kB * kN;       // 44,800,000
constexpr size_t OFF_ROT    = OFF_SCALE + (size_t)kB * kN * 3;  // 64,000,000

// scratch-in-output:
//   rec (B*V*2 float4 = 25.6 MB) -> opac region (25.6 MB, exact fit)
//   Vw  (B*V float4  = 12.8 MB)  -> scale region (76.8 MB)
// order: skin->Vw@scale; frame reads Vw@scale writes rec@opac;
// mr4 reads rec@opac writes means/rot; cos overwrites colors/opac/scale last.

// workspace layout (bytes); proven ws_size >= 20.03 MB (R2 ran in it)
constexpr size_t WS_A   = 0;        // B*J*12 floats
constexpr size_t WS_CNT = 32768;    // V ints (cursor/degree)
constexpr size_t WS_TRI = 135168;   // kCap*kV int4 = 16,000,000 B
// end ~= 16.14 MB
}

// ---------------------------------------------------------------------------
// Bucket fill: tri[slot][v] = (i0,i1,i2) for each face incident to v.
// ---------------------------------------------------------------------------
__global__ void fill_bucket_kernel(const int* __restrict__ faces,
                                   int* __restrict__ cursor,
                                   int4* __restrict__ tri) {
    int f = blockIdx.x * blockDim.x + threadIdx.x;
    if (f >= kF) return;
    int i0 = faces[f * 3 + 0];
    int i1 = faces[f * 3 + 1];
    int i2 = faces[f * 3 + 2];
    int4 rec = make_int4(i0, i1, i2, 0);
#pragma unroll
    for (int k = 0; k < 3; ++k) {
        int v = (k == 0) ? i0 : (k == 1) ? i1 : i2;
        int p = atomicAdd(&cursor[v], 1);
        if (p < kCap) tri[(size_t)p * kV + v] = rec;  // slot-major
    }
}

// ---------------------------------------------------------------------------
// Kernel 1: per-batch joint transform chain.
// ---------------------------------------------------------------------------
__global__ void jt_kernel(const float* __restrict__ pose,
                          const float* __restrict__ jr,
                          float* __restrict__ A) {
    int b = threadIdx.x;
    if (b >= kB) return;

    float Gr[9], Gt[3];
    for (int j = 0; j < kJ; ++j) {
        float ax = pose[b * (kJ * 3) + j * 3 + 0];
        float ay = pose[b * (kJ * 3) + j * 3 + 1];
        float az = pose[b * (kJ * 3) + j * 3 + 2];
        float t2 = ax * ax + ay * ay + az * az + 1e-12f;
        float th = sqrtf(t2);
        float inv = 1.0f / th;
        float ux = ax * inv, uy = ay * inv, uz = az * inv;
        float s = sinf(th), c = cosf(th), oc = 1.0f - c;
        float R[9];
        R[0] = 1.0f + oc * (-(uy * uy + uz * uz));
        R[1] = -s * uz + oc * (ux * uy);
        R[2] =  s * uy + oc * (ux * uz);
        R[3] =  s * uz + oc * (ux * uy);
        R[4] = 1.0f + oc * (-(ux * ux + uz * uz));
        R[5] = -s * ux + oc * (uy * uz);
        R[6] = -s * uy + oc * (ux * uz);
        R[7] =  s * ux + oc * (uy * uz);
        R[8] = 1.0f + oc * (-(ux * ux + uy * uy));

        float jx = jr[j * 3 + 0], jy = jr[j * 3 + 1], jz = jr[j * 3 + 2];

        if (j == 0) {
            for (int k = 0; k < 9; ++k) Gr[k] = R[k];
            Gt[0] = jx; Gt[1] = jy; Gt[2] = jz;
        } else {
            float pjx = jr[(j - 1) * 3 + 0];
            float pjy = jr[(j - 1) * 3 + 1];
            float pjz = jr[(j - 1) * 3 + 2];
            float ltx = jx - pjx, lty = jy - pjy, ltz = jz - pjz;
            float nR[9], nT[3];
            for (int r = 0; r < 3; ++r) {
                float g0 = Gr[r * 3 + 0], g1 = Gr[r * 3 + 1], g2 = Gr[r * 3 + 2];
                nR[r * 3 + 0] = g0 * R[0] + g1 * R[3] + g2 * R[6];
                nR[r * 3 + 1] = g0 * R[1] + g1 * R[4] + g2 * R[7];
                nR[r * 3 + 2] = g0 * R[2] + g1 * R[5] + g2 * R[8];
                nT[r] = g0 * ltx + g1 * lty + g2 * ltz + Gt[r];
            }
            for (int k = 0; k < 9; ++k) Gr[k] = nR[k];
            Gt[0] = nT[0]; Gt[1] = nT[1]; Gt[2] = nT[2];
        }

        float tgx = Gt[0] - (Gr[0] * jx + Gr[1] * jy + Gr[2] * jz);
        float tgy = Gt[1] - (Gr[3] * jx + Gr[4] * jy + Gr[5] * jz);
        float tgz = Gt[2] - (Gr[6] * jx + Gr[7] * jy + Gr[8] * jz);
        float* Ao = A + ((size_t)b * kJ + j) * 12;
        Ao[0] = Gr[0]; Ao[1] = Gr[1]; Ao[2]  = Gr[2]; Ao[3]  = tgx;
        Ao[4] = Gr[3]; Ao[5] = Gr[4]; Ao[6]  = Gr[5]; Ao[7]  = tgy;
        Ao[8] = Gr[6]; Ao[9] = Gr[7]; Ao[10] = Gr[8]; Ao[11] = tgz;
    }
}

// ---------------------------------------------------------------------------
// Kernel 2: LBS skinning -> float4 Vw (in the scale output region).
// ---------------------------------------------------------------------------
__global__ void skin_kernel(const float* __restrict__ A,
                            const float* __restrict__ sw,
                            const float* __restrict__ vt,
                            const float* __restrict__ scale,
                            const float* __restrict__ trans,
                            float4* __restrict__ Vw) {
    int b = blockIdx.y;
    int v = blockIdx.x * blockDim.x + threadIdx.x;
    __shared__ float sA[kJ * 12];
    if (threadIdx.x < kJ * 12) sA[threadIdx.x] = A[(size_t)b * kJ * 12 + threadIdx.x];
    __syncthreads();
    if (v >= kV) return;

    const float4* sw4 = (const float4*)(sw + (size_t)v * kJ);
    float w[kJ];
#pragma unroll
    for (int q = 0; q < 5; ++q) {
        float4 f = sw4[q];
        w[q * 4 + 0] = f.x; w[q * 4 + 1] = f.y;
        w[q * 4 + 2] = f.z; w[q * 4 + 3] = f.w;
    }

    float T[12];
#pragma unroll
    for (int k = 0; k < 12; ++k) T[k] = 0.0f;
#pragma unroll
    for (int j = 0; j < kJ; ++j) {
        float wj = w[j];
#pragma unroll
        for (int k = 0; k < 12; ++k) T[k] += wj * sA[j * 12 + k];
    }
    float x = vt[v * 3 + 0], y = vt[v * 3 + 1], z = vt[v * 3 + 2];
    float px = T[0] * x + T[1] * y + T[2]  * z + T[3];
    float py = T[4] * x + T[5] * y + T[6]  * z + T[7];
    float pz = T[8] * x + T[9] * y + T[10] * z + T[11];
    float s = scale[b];
    float tx = trans[b * 3 + 0], ty = trans[b * 3 + 1], tz = trans[b * 3 + 2];
    Vw[(size_t)b * kV + v] = make_float4(px * s + tx, py * s + ty, pz * s + tz, 0.0f);
}

// ---------------------------------------------------------------------------
// Kernel 3: per-(b,v) normal gather + tangent frame + branch-faithful quat.
// Writes packed 32B record {pos.xyz,_}, {fq} — one cache line per later gather.
// ---------------------------------------------------------------------------
__global__ void frame_kernel(const float4* __restrict__ Vw,
                             const int* __restrict__ cnt,
                             const int4* __restrict__ tri,
                             float4* __restrict__ rec) {
    int b = blockIdx.y;
    int v = blockIdx.x * blockDim.x + threadIdx.x;
    if (v >= kV) return;
    const float4* base = Vw + (size_t)b * kV;
    float4 me = base[v];

    int deg = min(cnt[v], kCap);
    float sx = 0.0f, sy = 0.0f, sz = 0.0f;
    for (int i = 0; i < deg; ++i) {
        int4 t = tri[(size_t)i * kV + v];   // coalesced across lanes
        float4 a  = base[t.x];
        float4 c1 = base[t.y];
        float4 c2 = base[t.z];
        float e1x = c1.x - a.x, e1y = c1.y - a.y, e1z = c1.z - a.z;
        float e2x = c2.x - a.x, e2y = c2.y - a.y, e2z = c2.z - a.z;
        sx += e1y * e2z - e1z * e2y;
        sy += e1z * e2x - e1x * e2z;
        sz += e1x * e2y - e1y * e2x;
    }

    float ninv = rsqrtf(sx * sx + sy * sy + sz * sz + 1e-12f);
    float nx = sx * ninv, ny = sy * ninv, nz = sz * ninv;

    bool small = fabsf(nx) < 0.9f;
    float refx = small ? 1.0f : 0.0f;
    float refz = small ? 0.0f : 1.0f;
    float d = refx * nx + refz * nz;
    float tx0 = refx - d * nx, ty0 = -d * ny, tz0 = refz - d * nz;
    float tinv = rsqrtf(tx0 * tx0 + ty0 * ty0 + tz0 * tz0 + 1e-12f);
    float tx = tx0 * tinv, ty = ty0 * tinv, tz = tz0 * tinv;

    float btx = ny * tz - nz * ty;
    float bty = nz * tx - nx * tz;
    float btz = nx * ty - ny * tx;

    // frame columns (t, bt, n) -> quaternion, branch-faithful vs reference
    float r00 = tx, r01 = btx, r02 = nx;
    float r10 = ty, r11 = bty, r12 = ny;
    float r20 = tz, r21 = btz, r22 = nz;
    float tr = r00 + r11 + r22;
    float q0, q1, q2, q3;
    if (tr > 0.0f) {
        float s = sqrtf(fmaxf(tr + 1.0f, kEps)) * 2.0f;
        q0 = 0.25f * s;
        q1 = (r21 - r12) / s;
        q2 = (r02 - r20) / s;
        q3 = (r10 - r01) / s;
    } else if (r00 > r11 && r00 > r22) {
        float s = sqrtf(fmaxf(1.0f + r00 - r11 - r22, kEps)) * 2.0f;
        q0 = (r21 - r12) / s;
        q1 = 0.25f * s;
        q2 = (r01 + r10) / s;
        q3 = (r02 + r20) / s;
    } else if (r11 > r22) {
        float s = sqrtf(fmaxf(1.0f + r11 - r00 - r22, kEps)) * 2.0f;
        q0 = (r02 - r20) / s;
        q1 = (r01 + r10) / s;
        q2 = 0.25f * s;
        q3 = (r12 + r21) / s;
    } else {
        float s = sqrtf(fmaxf(1.0f + r22 - r00 - r11, kEps)) * 2.0f;
        q0 = (r10 - r01) / s;
        q1 = (r02 + r20) / s;
        q2 = (r12 + r21) / s;
        q3 = 0.25f * s;
    }
    float qinv = rsqrtf(q0 * q0 + q1 * q1 + q2 * q2 + q3 * q3 + 1e-12f);
    q0 *= qinv; q1 *= qinv; q2 *= qinv; q3 *= qinv;

    size_t ro = ((size_t)b * kV + v) * 2;
    rec[ro + 0] = make_float4(me.x, me.y, me.z, 0.0f);
    rec[ro + 1] = make_float4(q0, q1, q2, q3);
}

// ---------------------------------------------------------------------------
// Kernel 4a: means + rotations, 4 gaussians per thread, all-float4 I/O.
// t/bt/n reconstructed from fq (exact for orthonormal frames).
// ---------------------------------------------------------------------------
__global__ void finalize_mr4_kernel(const float4* __restrict__ rec,
                                    const int* __restrict__ vidx,
                                    const float* __restrict__ poff,
                                    const float* __restrict__ quat,
                                    float* __restrict__ out) {
    int b = blockIdx.y;
    int qi = blockIdx.x * blockDim.x + threadIdx.x;
    if (qi >= kN / 4) return;
    int n0 = qi * 4;

    int4 vi = *(const int4*)(vidx + n0);
    const float4* rb = rec + (size_t)b * kV * 2;

    float4 p[4], fq[4];
    p[0] = rb[(size_t)vi.x * 2]; fq[0] = rb[(size_t)vi.x * 2 + 1];
    p[1] = rb[(size_t)vi.y * 2]; fq[1] = rb[(size_t)vi.y * 2 + 1];
    p[2] = rb[(size_t)vi.z * 2]; fq[2] = rb[(size_t)vi.z * 2 + 1];
    p[3] = rb[(size_t)vi.w * 2]; fq[3] = rb[(size_t)vi.w * 2 + 1];

    const float4* po = (const float4*)(poff + (size_t)n0 * 3);
    float4 oa = po[0], ob = po[1], oc = po[2];
    float off[4][3] = {{oa.x, oa.y, oa.z}, {oa.w, ob.x, ob.y},
                       {ob.z, ob.w, oc.x}, {oc.y, oc.z, oc.w}};

    const float4* lq4 = (const float4*)(quat + (size_t)n0 * 4);

    float m[4][3];
    float4 rotv[4];
#pragma unroll
    for (int k = 0; k < 4; ++k) {
        float w = fq[k].x, x = fq[k].y, y = fq[k].z, z = fq[k].w;
        // R(fq) columns = (t, bt, n)
        float tx = 1.0f - 2.0f * (y * y + z * z);
        float ty = 2.0f * (x * y + w * z);
        float tz = 2.0f * (x * z - w * y);
        float btx = 2.0f * (x * y - w * z);
        float bty = 1.0f - 2.0f * (x * x + z * z);
        float btz = 2.0f * (y * z + w * x);
        float nx = 2.0f * (x * z + w * y);
        float ny = 2.0f * (y * z - w * x);
        float nz = 1.0f - 2.0f * (x * x + y * y);

        float o0 = off[k][0], o1 = off[k][1], o2 = off[k][2];
        m[k][0] = p[k].x + o0 * tx + o1 * btx + o2 * nx;
        m[k][1] = p[k].y + o0 * ty + o1 * bty + o2 * ny;
        m[k][2] = p[k].z + o0 * tz + o1 * btz + o2 * nz;

        float4 lq = lq4[k];
        float lw = lq.x, lx = lq.y, ly = lq.z, lz = lq.w;
        float linv = rsqrtf(lw * lw + lx * lx + ly * ly + lz * lz + 1e-12f);
        lw *= linv; lx *= linv; ly *= linv; lz *= linv;

        rotv[k] = make_float4(w * lw - x * lx - y * ly - z * lz,
                              w * lx + x * lw + y * lz - z * ly,
                              w * ly - x * lz + y * lw + z * lx,
                              w * lz + x * ly - y * lx + z * lw);
    }

    size_t bn0 = (size_t)b * kN + n0;
    float4* mo = (float4*)(out + OFF_MEANS + bn0 * 3);
    mo[0] = make_float4(m[0][0], m[0][1], m[0][2], m[1][0]);
    mo[1] = make_float4(m[1][1], m[1][2], m[2][0], m[2][1]);
    mo[2] = make_float4(m[2][2], m[3][0], m[3][1], m[3][2]);
    float4* ro = (float4*)(out + OFF_ROT + bn0 * 4);
    ro[0] = rotv[0]; ro[1] = rotv[1]; ro[2] = rotv[2]; ro[3] = rotv[3];
}

// ---------------------------------------------------------------------------
// Kernel 4b: colors + opacity + scales (pure streaming; runs LAST, overwrites
// the rec/Vw scratch living in opac/scale).
// ---------------------------------------------------------------------------
__device__ __forceinline__ float sigm(float x) {
    return 1.0f / (1.0f + __expf(-x));
}
__device__ __forceinline__ float eclip(float x) {
    return fminf(fmaxf(__expf(x), 0.0005f), 0.05f);
}

__global__ void finalize_cos_kernel(const float* __restrict__ craw,
                                    const float* __restrict__ oraw,
                                    const float* __restrict__ lsc,
                                    float* __restrict__ out) {
    int b = blockIdx.y;
    int q = blockIdx.x * blockDim.x + threadIdx.x;
    if (q >= kN / 4) return;
    int n0 = q * 4;

    const float4* cr4 = (const float4*)(craw + (size_t)n0 * 3);
    float4 ca = cr4[0], cb = cr4[1], cc = cr4[2];
    float4 ov = *(const float4*)(oraw + n0);
    const float4* ls4 = (const float4*)(lsc + (size_t)n0 * 3);
    float4 la = ls4[0], lb = ls4[1], lc = ls4[2];

    float4 sa = make_float4(sigm(ca.x), sigm(ca.y), sigm(ca.z), sigm(ca.w));
    float4 sb = make_float4(sigm(cb.x), sigm(cb.y), sigm(cb.z), sigm(cb.w));
    float4 sc = make_float4(sigm(cc.x), sigm(cc.y), sigm(cc.z), sigm(cc.w));
    float4 so = make_float4(sigm(ov.x), sigm(ov.y), sigm(ov.z), sigm(ov.w));
    float4 ea = make_float4(eclip(la.x), eclip(la.y), eclip(la.z), eclip(la.w));
    float4 eb = make_float4(eclip(lb.x), eclip(lb.y), eclip(lb.z), eclip(lb.w));
    float4 ec = make_float4(eclip(lc.x), eclip(lc.y), eclip(lc.z), eclip(lc.w));

    size_t bn0 = (size_t)b * kN + n0;
    float4* co = (float4*)(out + OFF_COLORS + bn0 * 3);
    co[0] = sa; co[1] = sb; co[2] = sc;
    *(float4*)(out + OFF_OPAC + bn0) = so;
    float4* sco = (float4*)(out + OFF_SCALE + bn0 * 3);
    sco[0] = ea; sco[1] = eb; sco[2] = ec;
}

extern "C" void kernel_launch(void* const* d_in, const int* in_sizes, int n_in,
                              void* d_out, int out_size, void* d_ws, size_t ws_size,
                              hipStream_t stream) {
    const float* pose  = (const float*)d_in[0];
    const float* trans = (const float*)d_in[1];
    const float* scale = (const float*)d_in[2];
    const float* vt    = (const float*)d_in[3];
    const float* sw    = (const float*)d_in[4];
    const float* jr    = (const float*)d_in[5];
    const float* poff  = (const float*)d_in[6];
    const float* craw  = (const float*)d_in[7];
    const float* oraw  = (const float*)d_in[8];
    const float* lsc   = (const float*)d_in[9];
    const float* quat  = (const float*)d_in[10];
    const int*   vidx  = (const int*)d_in[11];
    const int*   faces = (const int*)d_in[12];
    float* out = (float*)d_out;
    char* ws = (char*)d_ws;

    float* A   = (float*)(ws + WS_A);
    int*   cnt = (int*)(ws + WS_CNT);
    int4*  tri = (int4*)(ws + WS_TRI);

    // scratch inside d_out
    float4* rec = (float4*)(out + OFF_OPAC);   // B*V*2 float4 = 25.6 MB (exact)
    float4* Vw  = (float4*)(out + OFF_SCALE);  // B*V float4 = 12.8 MB of 76.8

    dim3 gV((kV + 255) / 256, kB);
    dim3 gQ((kN / 4 + 255) / 256, kB);

    // adjacency buckets (batch-independent)
    hipMemsetAsync(cnt, 0, kV * sizeof(int), stream);
    fill_bucket_kernel<<<(kF + 255) / 256, 256, 0, stream>>>(faces, cnt, tri);

    // joints + skinning
    jt_kernel<<<1, 64, 0, stream>>>(pose, jr, A);
    skin_kernel<<<gV, 256, 0, stream>>>(A, sw, vt, scale, trans, Vw);

    // per-(b,v) frame + quaternion records
    frame_kernel<<<gV, 256, 0, stream>>>(Vw, cnt, tri, rec);

    // means + rotations (gathers one 32B record per gaussian)
    finalize_mr4_kernel<<<gQ, 256, 0, stream>>>(rec, vidx, poff, quat, out);

    // colors + opacity + scales (overwrites scratch, runs last)
    finalize_cos_kernel<<<gQ, 256, 0, stream>>>(craw, oraw, lsc, out);
}